// Round 8
// baseline (211.646 us; speedup 1.0000x reference)
//
#include <hip/hip_runtime.h>
#include <hip/hip_bf16.h>
#include <stdint.h>

typedef unsigned short u16;
typedef u16   us8    __attribute__((ext_vector_type(8)));
typedef __bf16 bf16x8 __attribute__((ext_vector_type(8)));
typedef float f32x4  __attribute__((ext_vector_type(4)));

#define DEV static __device__ __forceinline__

DEV u16 f2bf(float f) {                       // fp32 -> bf16 RNE
  uint32_t u = __builtin_bit_cast(uint32_t, f);
  u += 0x7FFFu + ((u >> 16) & 1u);
  return (u16)(u >> 16);
}
DEV float bf2f(u16 s) { return __builtin_bit_cast(float, (uint32_t)s << 16); }

DEV void gl16(const void* g, void* l) {       // async global->LDS, 16B/lane
  __builtin_amdgcn_global_load_lds((const __attribute__((address_space(1))) void*)g,
                                   (__attribute__((address_space(3))) void*)l, 16, 0, 0);
}

// ------- fused fp32 -> bf16 convert for x, Wq, Wk, Wv + bias concat -------
__global__ __launch_bounds__(256) void k_cvt_all(
    const float* __restrict__ x, const float* __restrict__ wq,
    const float* __restrict__ wk, const float* __restrict__ wv,
    const float* __restrict__ bq, const float* __restrict__ bk,
    u16* __restrict__ out, float* __restrict__ bQK, int xn4, int wn4) {
  int i = blockIdx.x * 256 + threadIdx.x;
  const int cvt_tot = xn4 + 3 * wn4;
  if (i < cvt_tot) {
    const float* src;
    int idx;
    if (i < xn4) { src = x; idx = i; }
    else {
      int j = i - xn4;
      if (j < wn4) { src = wq; idx = j; }
      else if (j < 2 * wn4) { src = wk; idx = j - wn4; }
      else { src = wv; idx = j - 2 * wn4; }
    }
    float4 v = reinterpret_cast<const float4*>(src)[idx];
    uint2 o;
    o.x = (uint32_t)f2bf(v.x) | ((uint32_t)f2bf(v.y) << 16);
    o.y = (uint32_t)f2bf(v.z) | ((uint32_t)f2bf(v.w) << 16);
    reinterpret_cast<uint2*>(out)[i] = o;
  } else {
    int j = i - cvt_tot;                 // bias copy: bq(256 f4) bk(256 f4)
    if (j < 256)      reinterpret_cast<float4*>(bQK)[j] = reinterpret_cast<const float4*>(bq)[j];
    else if (j < 512) reinterpret_cast<float4*>(bQK)[j] = reinterpret_cast<const float4*>(bk)[j - 256];
  }
}

// ============ 128x256-tile, BK=32, 3-slot, 4-wave NT GEMM body ==============
// C[m,n] = alpha * sum_k A[m,k]*B[n,k] (+bias).  A,B bf16 row-major K-contig.
// 256 threads = 4 waves (1M x 4N), per-wave output 128x64 (acc[8][4] f32x4).
// LDS: A[3 slot][128x32]=24KB, B[3 slot][256x32]=48KB -> 72KB -> 2 blocks/CU.
// One phase per K-tile: 12 ds_reads (3 SB0 clusters) || stage(t+2) 6 gl16 ->
// LGKM(7/2/0)-gated MFMA n-sweeps -> vmcnt(6) (vmcnt(0) at tail) -> s_barrier.
// 3-slot rotation: stage(t+2) writes slot (t+2)%3, disjoint from slots t/t+1
// being read; t-1's reads done before barrier(t-1) -> race-free, 1 barrier.
// Swizzle: 4 slots/row (64B), phys slot = logical ^ ((row>>1)&3) -> 2-way
// bank access (free, m136); stage pre-swizzles the GLOBAL source column.
#define SB0 __builtin_amdgcn_sched_barrier(0)
#define LGKM(N) do { asm volatile("s_waitcnt lgkmcnt(" #N ")" ::: "memory"); \
                     __builtin_amdgcn_sched_barrier(0); } while (0)

template <bool OUT_BF16, int BIAS_MODE>
DEV void gemm_body32(const u16* __restrict__ A, const u16* __restrict__ B,
                     void* __restrict__ Cv, const float* __restrict__ bias,
                     int K, int lda, int ldb, int ldc, float alpha,
                     int m0, int n0, long long cbase, u16* lds) {
  u16* AsB = lds;            // [3][4096] u16
  u16* BsB = lds + 12288;    // [3][8192] u16
  const int t = threadIdx.x;          // 0..255
  const int lane = t & 63;
  const int wid = t >> 6;             // wave n-index 0..3
  const int l15 = lane & 15, l4 = lane >> 4;

  // staging geometry: thread t -> phys row srow(+j*64), phys slot t&3.
  // swz(row) = (row>>1)&3 is invariant under row += 64 -> one sc for all j.
  const int srow = t >> 2, sslot = t & 3;
  const int sc = (sslot ^ ((srow >> 1) & 3)) * 8;
  const u16* Asrc = A + (long long)(m0 + srow) * lda + sc;
  const u16* Bsrc = B + (long long)(n0 + srow) * ldb + sc;
  const long long a64 = 64LL * lda, b64 = 64LL * ldb;

#define STG(kt, sl) { const long long ko = (long long)(kt) * 32;               \
    u16* ad = AsB + (sl) * 4096 + t * 8;                                       \
    u16* bd = BsB + (sl) * 8192 + t * 8;                                       \
    gl16(Asrc + ko, ad); gl16(Asrc + a64 + ko, ad + 2048);                     \
    gl16(Bsrc + ko, bd); gl16(Bsrc + b64 + ko, bd + 2048);                     \
    gl16(Bsrc + 2 * b64 + ko, bd + 4096); gl16(Bsrc + 3 * b64 + ko, bd + 6144); }

  // read-side: logical k-slice l4, phys slot = l4 ^ ((l15>>1)&3) (rows = ..+l15,
  // all row-block offsets are multiples of 4 -> swz depends only on l15).
  const int cs = (l4 ^ ((l15 >> 1) & 3)) * 8;
#define LD(base, row) (*(const bf16x8*)&(base)[(row) * 32 + cs])

  f32x4 acc[8][4];
#pragma unroll
  for (int i = 0; i < 8; ++i)
#pragma unroll
    for (int j = 0; j < 4; ++j) { f32x4 z = {0.f, 0.f, 0.f, 0.f}; acc[i][j] = z; }

  const int NT = K >> 5;   // K-tiles of 32 (ours: 32 or 64)

  // prologue: stage tiles 0 and 1; wait tile0 (12 in flight -> leave <=6)
  STG(0, 0); STG(1, 1);
  asm volatile("s_waitcnt vmcnt(6)" ::: "memory");
  __builtin_amdgcn_s_barrier();

#define MMA(f_, n_) acc[f_][n_] = __builtin_amdgcn_mfma_f32_16x16x32_bf16(      \
    af[f_], bf[n_], acc[f_][n_], 0, 0, 0)

  int slr = 0, sl2 = 2;    // read slot = tt%3, stage slot = (tt+2)%3
  for (int tt = 0; tt < NT; ++tt) {
    const u16* Ah = AsB + slr * 4096;
    const u16* Bh = BsB + slr * 8192;
    const int brow = wid * 64 + l15;
    bf16x8 af[8], bf[4];
    // C1: bf0, af0..af3 (5 reads)
    bf[0] = LD(Bh, brow);
    af[0] = LD(Ah, l15);      af[1] = LD(Ah, 16 + l15);
    af[2] = LD(Ah, 32 + l15); af[3] = LD(Ah, 48 + l15);
    SB0;
    // C2: af4..af7, bf1 (5)
    af[4] = LD(Ah, 64 + l15); af[5] = LD(Ah, 80 + l15);
    af[6] = LD(Ah, 96 + l15); af[7] = LD(Ah, 112 + l15);
    bf[1] = LD(Bh, brow + 16);
    SB0;
    // C3: bf2, bf3 (2)
    bf[2] = LD(Bh, brow + 32); bf[3] = LD(Bh, brow + 48);
    SB0;
    const bool s2 = (tt + 2 < NT);
    if (s2) STG(tt + 2, sl2);
    SB0;
    LGKM(7);                 // C1 landed
    __builtin_amdgcn_s_setprio(1);
    MMA(0, 0); MMA(1, 0); MMA(2, 0); MMA(3, 0);
    LGKM(2);                 // C2 landed
    MMA(4, 0); MMA(5, 0); MMA(6, 0); MMA(7, 0);
    MMA(0, 1); MMA(1, 1); MMA(2, 1); MMA(3, 1);
    MMA(4, 1); MMA(5, 1); MMA(6, 1); MMA(7, 1);
    LGKM(0);                 // C3 landed
    MMA(0, 2); MMA(1, 2); MMA(2, 2); MMA(3, 2);
    MMA(4, 2); MMA(5, 2); MMA(6, 2); MMA(7, 2);
    MMA(0, 3); MMA(1, 3); MMA(2, 3); MMA(3, 3);
    MMA(4, 3); MMA(5, 3); MMA(6, 3); MMA(7, 3);
    __builtin_amdgcn_s_setprio(0);
    if (s2) { asm volatile("s_waitcnt vmcnt(6)" ::: "memory"); }
    else    { asm volatile("s_waitcnt vmcnt(0)" ::: "memory"); }
    __builtin_amdgcn_s_barrier();
    slr = (slr == 2) ? 0 : slr + 1;
    sl2 = (sl2 == 2) ? 0 : sl2 + 1;
  }
#undef STG
#undef LD
#undef MMA

  // epilogue: C/D layout col=lane&15, row=(lane>>4)*4+reg (m89-verified)
#pragma unroll
  for (int f = 0; f < 8; ++f) {
    const int grow0 = m0 + f * 16 + l4 * 4;
#pragma unroll
    for (int n = 0; n < 4; ++n) {
      const int gcol = n0 + wid * 64 + n * 16 + l15;
      float bc = 0.f;
      if (BIAS_MODE == 1) bc = bias[gcol];
#pragma unroll
      for (int r = 0; r < 4; ++r) {
        float bv_ = (BIAS_MODE == 2) ? bias[grow0 + r] : bc;
        float v = acc[f][n][r] * alpha + bv_;
        long long idx = cbase + (long long)(grow0 + r) * ldc + gcol;
        if constexpr (OUT_BF16) ((u16*)Cv)[idx] = f2bf(v);
        else                    ((float*)Cv)[idx] = v;
      }
    }
  }
}

// ---- standalone batched NT GEMM (scores / outputs), XCD-swizzled ----
template <bool OUT_BF16>
__global__ __launch_bounds__(256, 2) void k_gemm32(
    const u16* __restrict__ A, const u16* __restrict__ B,
    void* __restrict__ Cv, int K, int lda, int ldb, int ldc,
    long long sA, long long sB, long long sC, float alpha, int gx, int gy) {
  __shared__ alignas(16) u16 lds[36864];   // 72 KiB
  const int nwg = gridDim.x;
  int lin = blockIdx.x;
  lin = (lin & 7) * (nwg >> 3) + (lin >> 3);
  const int gxy = gx * gy;
  const int bz = lin / gxy;
  const int rem = lin - bz * gxy;
  const int by = rem / gx;
  const int bx = rem - by * gx;
  gemm_body32<OUT_BF16, 0>(A + (long long)bz * sA, B + (long long)bz * sB, Cv,
                           nullptr, K, lda, ldb, ldc, alpha,
                           by * 128, bx * 256, (long long)bz * sC, lds);
}

// ---- K2: QK-proj (512 blk) + V^T-proj (256 blk) + X^T transpose (2048) ----
// QKb[8192][2048] = X @ [Wq;Wk]^T + b.  VTX[1024][16384]: cols 0..8191 =
// V^T = Wv @ X^T + bv (row bias), cols 8192.. = X^T.  256 threads/block.
__global__ __launch_bounds__(256, 2) void k_proj(
    const u16* __restrict__ xb, const u16* __restrict__ Wqkv,
    const float* __restrict__ bQK, const float* __restrict__ bv,
    u16* __restrict__ QKb, u16* __restrict__ VTX) {
  __shared__ alignas(16) u16 lds[36864];
  const int bid = blockIdx.x;
  if (bid < 512) {            // QK-proj: M=8192 (gy=64), N=2048 (gx=8)
    int lin = (bid & 7) * 64 + (bid >> 3);
    const int by = lin >> 3, bx = lin & 7;
    gemm_body32<true, 1>(xb, Wqkv, QKb, bQK, 1024, 1024, 1024, 2048, 1.0f,
                         by * 128, bx * 256, 0, lds);
  } else if (bid < 768) {     // V^T-proj: M=1024 (gy=8), N=8192 (gx=32)
    int b2 = bid - 512;
    int lin = (b2 & 7) * 32 + (b2 >> 3);
    const int by = lin >> 5, bx = lin & 31;
    gemm_body32<true, 2>(Wqkv + 2048 * 1024, xb, VTX, bv, 1024, 1024, 1024,
                         16384, 1.0f, by * 128, bx * 256, 0, lds);
  } else {                    // X^T: 64x64 tiles, 2048 blocks, 256 threads
    const int tb = bid - 768;
    const int r0 = (tb >> 4) * 64, c0 = (tb & 15) * 64;   // row/col in x
    const int tx = threadIdx.x & 63, ty = threadIdx.x >> 6;
    u16* tile = lds;          // [64][65]
#pragma unroll
    for (int i = 0; i < 64; i += 4)
      tile[(ty + i) * 65 + tx] = xb[(long long)(r0 + ty + i) * 1024 + c0 + tx];
    __syncthreads();
#pragma unroll
    for (int i = 0; i < 64; i += 4)
      VTX[(long long)(c0 + ty + i) * 16384 + 8192 + r0 + tx] = tile[tx * 65 + ty + i];
  }
}

// ---------------- in-place row softmax over 2048 bf16 cols ----------------
__global__ __launch_bounds__(256) void k_softmax(u16* __restrict__ P) {
  const long long row = blockIdx.x;
  u16* p = P + row * 2048;
  const int t = threadIdx.x;
  us8 v = *reinterpret_cast<const us8*>(&p[t * 8]);
  float f[8];
#pragma unroll
  for (int j = 0; j < 8; ++j) f[j] = bf2f(v[j]);
  float m = f[0];
#pragma unroll
  for (int j = 1; j < 8; ++j) m = fmaxf(m, f[j]);
#pragma unroll
  for (int o = 32; o > 0; o >>= 1) m = fmaxf(m, __shfl_xor(m, o));
  __shared__ float redm[4], reds[4];
  if ((t & 63) == 0) redm[t >> 6] = m;
  __syncthreads();
  m = fmaxf(fmaxf(redm[0], redm[1]), fmaxf(redm[2], redm[3]));
  float s = 0.f;
#pragma unroll
  for (int j = 0; j < 8; ++j) {
    f[j] = __expf(f[j] - m);
    s += f[j];
  }
#pragma unroll
  for (int o = 32; o > 0; o >>= 1) s += __shfl_xor(s, o);
  if ((t & 63) == 0) reds[t >> 6] = s;
  __syncthreads();
  s = reds[0] + reds[1] + reds[2] + reds[3];
  const float inv = 1.0f / s;
  us8 o8;
#pragma unroll
  for (int j = 0; j < 8; ++j) o8[j] = f2bf(f[j] * inv);
  *reinterpret_cast<us8*>(&p[t * 8]) = o8;
}

// ---- 64x64-tile bf16 transpose (square, same ld both sides, z-batched) ----
__global__ __launch_bounds__(512) void k_tr64(const u16* __restrict__ in,
                                              u16* __restrict__ out,
                                              int ld, long long sIO) {
  __shared__ u16 tile[64 * 65];
  const long long base = (long long)blockIdx.z * sIO;
  const int r0 = blockIdx.y * 64, c0 = blockIdx.x * 64;
  const int tx = threadIdx.x & 63, ty = threadIdx.x >> 6;
#pragma unroll
  for (int i = 0; i < 64; i += 8)
    tile[(ty + i) * 65 + tx] = in[base + (long long)(r0 + ty + i) * ld + c0 + tx];
  __syncthreads();
#pragma unroll
  for (int i = 0; i < 64; i += 8)
    out[base + (long long)(c0 + ty + i) * ld + r0 + tx] = tile[tx * 65 + ty + i];
}

extern "C" void kernel_launch(void* const* d_in, const int* in_sizes, int n_in,
                              void* d_out, int out_size, void* d_ws, size_t ws_size,
                              hipStream_t stream) {
  (void)in_sizes; (void)n_in; (void)out_size;
  const float* x  = (const float*)d_in[0];
  const float* Wq = (const float*)d_in[1];
  const float* bq = (const float*)d_in[2];
  const float* Wk = (const float*)d_in[3];
  const float* bk = (const float*)d_in[4];
  const float* Wv = (const float*)d_in[5];
  const float* bv = (const float*)d_in[6];
  float* out = (float*)d_out;

  const int B = 4, S = 2048, D = 1024;
  const long long MX = (long long)B * S;  // 8192

  const long long need = MX * D * 2              // xb
                       + 3LL * D * D * 2         // Wqkv (contiguous after xb)
                       + 2048 * 4                // bQK
                       + MX * 2 * D * 2          // QKb [8192][2048]
                       + 2LL * B * S * S * 2     // P, PT (adjacent)
                       + (long long)D * 16384 * 2; // VTX [1024][16384]
  if ((long long)ws_size < need) return;

  char* w = (char*)d_ws;
  u16*   xb   = (u16*)w;   w += MX * D * 2;
  u16*   Wqkv = (u16*)w;   w += 3LL * D * D * 2;  // = xb + MX*D (contiguous)
  float* bQK  = (float*)w; w += 2048 * 4;
  u16*   QKb  = (u16*)w;   w += MX * 2 * D * 2;
  u16*   P    = (u16*)w;   w += (long long)B * S * S * 2;
  u16*   PT   = (u16*)w;   w += (long long)B * S * S * 2;   // = P + 4*S*S
  u16*   VTX  = (u16*)w;   w += (long long)D * 16384 * 2;
  (void)Wqkv; (void)PT;

  dim3 blk256(256), blk512(512);

  // K1: fused converts (xb+Wqkv contiguous) + bias concat (bq|bk -> bQK)
  {
    int xn4 = (int)(MX * D / 4);          // 2097152
    int wn4 = D * D / 4;                  // 262144
    int tot = xn4 + 3 * wn4 + 512;        // + 512 float4 bias units
    k_cvt_all<<<dim3((tot + 255) / 256), blk256, 0, stream>>>(
        x, Wq, Wk, Wv, bq, bk, xb, bQK, xn4, wn4);
  }

  // K2: QK-proj (512) + VT-proj (256) + X^T (2048)  -- 256-thread blocks
  k_proj<<<dim3(512 + 256 + 2048), blk256, 0, stream>>>(xb, Wqkv, bQK, bv, QKb, VTX);

  // K3: S = (Q @ K^T)/32 per batch: M=N=2048, K=1024 -> P bf16 (512 blocks)
  k_gemm32<true><<<dim3(512), blk256, 0, stream>>>(
      QKb, QKb + D, P, D, 2 * D, 2 * D, S,
      (long long)S * 2 * D, (long long)S * 2 * D, (long long)S * S,
      0.03125f, 8, 16);

  // K4: softmax rows in place
  k_softmax<<<dim3((int)(B * S)), blk256, 0, stream>>>(P);

  // K5: P -> PT (64x64 tiles)
  k_tr64<<<dim3(32, 32, 4), blk512, 0, stream>>>(P, PT, S, (long long)S * S);

  // K6: merged z<4 -> out1[z] = NT(P_z, VT_z); z>=4 -> out2[z-4] = NT(PT, XT)
  // A = P + z*S*S (PT contiguous); B = VTX + z*2048 (XT = cols 8192+)
  k_gemm32<false><<<dim3(512), blk256, 0, stream>>>(
      P, VTX, out, S, S, 16384, D,
      (long long)S * S, 2048, (long long)S * D, 1.0f, 4, 16);
}